// Round 2
// baseline (631.094 us; speedup 1.0000x reference)
//
#include <hip/hip_runtime.h>
#include <stdint.h>

#define N      8192
#define FEAT   512
#define HID    64
#define NH     4
#define C1     256          // NH*HID
#define PCH    80           // per-head c width incl. Z tile (64 data + 16)
#define TC     320          // NH*PCH
#define NCLS   16
#define C2     32           // phase-B c width (16 data + 16 Z tile)
#define IPB    8            // rows per block in k1

typedef __attribute__((ext_vector_type(8))) short bf16x8;
typedef __attribute__((ext_vector_type(4))) float f32x4;

__device__ __forceinline__ float b2f(uint16_t u){
  uint32_t x = ((uint32_t)u) << 16;
  return __builtin_bit_cast(float, x);
}
__device__ __forceinline__ uint16_t f2b(float f){
  uint32_t x = __builtin_bit_cast(uint32_t, f);
  uint32_t r = (x + 0x7fffu + ((x >> 16) & 1u)) >> 16;
  return (uint16_t)r;
}
__device__ __forceinline__ float lrelu(float v, float a){ return fmaxf(v, a * v); }

// ---------------------------------------------------------------- k0: Wh -> WhT[k][cc][f]  (fp32)
__global__ void k0_wht(const float* __restrict__ Wh, float* __restrict__ WhT){
  int idx = blockIdx.x * 256 + threadIdx.x;       // 131072 elems, 512 blocks
  int k = idx >> 15;
  int r = idx & 32767;
  int cc = r >> 9, f = r & 511;
  WhT[idx] = Wh[k * 32768 + f * 64 + cc];
}

// ---------------------------------------------------------------- k1: H = x @ Wh  (+ f1,f2)  fp32 in, bf16 H out
__global__ __launch_bounds__(256) void k1_h(const float* __restrict__ x,
    const float* __restrict__ WhT, const float* __restrict__ ah,
    uint16_t* __restrict__ H, float* __restrict__ f1, float* __restrict__ f2)
{
  __shared__ float4 xs[IPB][128];
  int t = threadIdx.x;
  int i0 = blockIdx.x * IPB;
  for (int r = t; r < IPB * 128; r += 256){
    int ii = r >> 7, o = r & 127;
    xs[ii][o] = *((const float4*)(x + (size_t)(i0 + ii) * FEAT) + o);
  }
  __syncthreads();
  int k = t >> 6, cc = t & 63;
  const float4* wrow = (const float4*)(WhT + k * 32768 + cc * 512);
  float acc[IPB] = {};
  for (int f4 = 0; f4 < 128; ++f4){
    float4 wv = wrow[f4];
    #pragma unroll
    for (int ii = 0; ii < IPB; ++ii){
      float4 xv = xs[ii][f4];
      acc[ii] += xv.x * wv.x + xv.y * wv.y + xv.z * wv.z + xv.w * wv.w;
    }
  }
  float a1 = ah[k * 128 + cc], a2 = ah[k * 128 + 64 + cc];
  #pragma unroll
  for (int ii = 0; ii < IPB; ++ii){
    int i = i0 + ii;
    H[(size_t)i * C1 + t] = f2b(acc[ii]);
    float c1v = acc[ii] * a1, c2v = acc[ii] * a2;
    #pragma unroll
    for (int off = 32; off; off >>= 1){
      c1v += __shfl_down(c1v, off);
      c2v += __shfl_down(c2v, off);
    }
    if (cc == 0){ f1[k * N + i] = c1v; f2[k * N + i] = c2v; }
  }
}

// ---------------------------------------------------------------- k2a: HT[k][p<64][i] = H[i][k*64+p]
__global__ void k2a_htT(const uint16_t* __restrict__ H, uint16_t* __restrict__ HT){
  __shared__ uint16_t tile[64][65];
  int bid = blockIdx.x;           // 128 i-tiles x 4 heads
  int k = bid & 3, it = bid >> 2;
  int i0 = it * 64;
  int t = threadIdx.x;
  #pragma unroll
  for (int r = 0; r < 4; ++r){
    int ii = r * 16 + (t >> 4);
    int pp = (t & 15) * 4;
    uint2 v = *(const uint2*)(H + (size_t)(i0 + ii) * C1 + k * 64 + pp);
    const uint16_t* s = (const uint16_t*)&v;
    tile[pp + 0][ii] = s[0]; tile[pp + 1][ii] = s[1];
    tile[pp + 2][ii] = s[2]; tile[pp + 3][ii] = s[3];
  }
  __syncthreads();
  #pragma unroll
  for (int r = 0; r < 4; ++r){
    int pp = r * 16 + (t >> 4);
    int ii = (t & 15) * 4;
    uint2 v;
    uint16_t* s = (uint16_t*)&v;
    s[0] = tile[pp][ii + 0]; s[1] = tile[pp][ii + 1];
    s[2] = tile[pp][ii + 2]; s[3] = tile[pp][ii + 3];
    *(uint2*)(HT + (size_t)k * (PCH * N) + (size_t)pp * N + i0 + ii) = v;
  }
}

// ---------------------------------------------------------------- k2b: HT rows 64..79 (ones + zeros)
__global__ void k2b_fill(uint16_t* __restrict__ HT){
  int fidx = blockIdx.x * 256 + threadIdx.x;      // 65536 uint4 units
  int k = fidx >> 14;
  int rem = fidx & 16383;
  int p = 64 + (rem >> 10);
  int i0 = (rem & 1023) << 3;
  uint32_t w = (p == 64) ? 0x3F803F80u : 0u;
  uint4 v = {w, w, w, w};
  *((uint4*)(HT + (size_t)k * (PCH * N) + (size_t)p * N + i0)) = v;
}

// ---------------------------------------------------------------- k3: phase-A masked-softmax GEMM
__global__ __launch_bounds__(256, 2) void k3_attA(const int* __restrict__ adj,
    const uint16_t* __restrict__ HT, const float* __restrict__ f1,
    const float* __restrict__ f2, float* __restrict__ accA)
{
  __shared__ uint16_t Pl[NH][64][48];
  __shared__ uint16_t Hl[TC][48];
  __shared__ float f1s[NH][64];

  const int t = threadIdx.x;
  const int ibl = blockIdx.x >> 2;
  const int js = blockIdx.x & 3;
  const int gi0 = ibl * 64;

  { int k = t >> 6, ii = t & 63; f1s[k][ii] = f1[k * N + gi0 + ii]; }

  const int tj   = t & 31;
  const int half = t >> 5;          // 0..7
  const int lane = t & 63;
  const int wid  = t >> 6;          // head owned by this wave
  const int m    = lane & 15;
  const int q    = lane >> 4;

  f32x4 acc[4][5] = {};
  const int* arow0 = adj + (size_t)(gi0 + half) * N + tj;

  for (int jc = 0; jc < 64; ++jc){
    const int gj = js * 2048 + jc * 32;
    float f2v0 = f2[0 * N + gj + tj];
    float f2v1 = f2[1 * N + gj + tj];
    float f2v2 = f2[2 * N + gj + tj];
    float f2v3 = f2[3 * N + gj + tj];
    int av[8];
    #pragma unroll
    for (int r = 0; r < 8; ++r) av[r] = arow0[(size_t)(8 * r) * N + gj];

    __syncthreads();                 // previous iter's LDS reads complete
    #pragma unroll
    for (int r = 0; r < 5; ++r){     // stage HT chunk: 320 rows x 32 j
      int idx = t + 256 * r;
      int p = idx >> 2, o4 = idx & 3;
      *(uint4*)&Hl[p][o4 * 8] = *(const uint4*)(HT + (size_t)p * N + gj + o4 * 8);
    }
    #pragma unroll
    for (int r = 0; r < 8; ++r){     // stage P: 64 i x 32 j x 4 heads
      int i = half + 8 * r;
      int a = av[r];
      float s0 = f1s[0][i] + f2v0;
      float s1 = f1s[1][i] + f2v1;
      float s2 = f1s[2][i] + f2v2;
      float s3 = f1s[3][i] + f2v3;
      float w0 = (a > 0) ? __expf(lrelu(s0, 0.2f)) : 0.f;
      float w1 = (a > 0) ? __expf(lrelu(s1, 0.2f)) : 0.f;
      float w2 = (a > 0) ? __expf(lrelu(s2, 0.2f)) : 0.f;
      float w3 = (a > 0) ? __expf(lrelu(s3, 0.2f)) : 0.f;
      Pl[0][i][tj] = f2b(w0);
      Pl[1][i][tj] = f2b(w1);
      Pl[2][i][tj] = f2b(w2);
      Pl[3][i][tj] = f2b(w3);
    }
    __syncthreads();

    bf16x8 af[4];
    #pragma unroll
    for (int it = 0; it < 4; ++it)
      af[it] = *(const bf16x8*)&Pl[wid][it * 16 + m][q * 8];
    #pragma unroll
    for (int ct = 0; ct < 5; ++ct){
      bf16x8 bfr = *(const bf16x8*)&Hl[wid * PCH + ct * 16 + m][q * 8];
      #pragma unroll
      for (int it = 0; it < 4; ++it)
        acc[it][ct] = __builtin_amdgcn_mfma_f32_16x16x32_bf16(af[it], bfr, acc[it][ct], 0, 0, 0);
    }
  }

  #pragma unroll
  for (int it = 0; it < 4; ++it)
    #pragma unroll
    for (int ct = 0; ct < 5; ++ct)
      #pragma unroll
      for (int reg = 0; reg < 4; ++reg){
        int gi = gi0 + it * 16 + q * 4 + reg;
        int c  = wid * PCH + ct * 16 + m;
        accA[((size_t)js * N + gi) * TC + c] = acc[it][ct][reg];
      }
}

// ---------------------------------------------------------------- k4: reduce partials -> xcat (lrelu 0.01)
__global__ void k4_redA(const float* __restrict__ accA, uint16_t* __restrict__ xcat){
  int i = blockIdx.x;
  int t = threadIdx.x;
  int k = t >> 6, cc = t & 63;
  size_t base = (size_t)i * TC + k * PCH;
  float v = 0.f, Z = 0.f;
  #pragma unroll
  for (int js = 0; js < 4; ++js){
    const float* p = accA + (size_t)js * N * TC + base;
    v += p[cc];
    Z += p[64];
  }
  float r = v / Z;
  xcat[(size_t)i * C1 + t] = f2b(lrelu(r, 0.01f));
}

// ---------------------------------------------------------------- k5: h2 = xcat@Wo, f1o/f2o, h2T(+ones)
__global__ __launch_bounds__(256) void k5_h2(const uint16_t* __restrict__ xcat,
    const float* __restrict__ Wo, const float* __restrict__ ao,
    uint16_t* __restrict__ h2T, float* __restrict__ f1o, float* __restrict__ f2o)
{
  __shared__ uint16_t xs[16][256];
  int t = threadIdx.x;
  int i0 = blockIdx.x * 16;
  #pragma unroll
  for (int r = 0; r < 2; ++r){
    int idx = t + 256 * r;
    int ii = idx >> 5, o4 = idx & 31;
    *(uint4*)&xs[ii][o4 * 8] = *(const uint4*)(xcat + (size_t)(i0 + ii) * C1 + o4 * 8);
  }
  __syncthreads();
  int ii = t >> 4, c = t & 15;
  float acc = 0.f;
  for (int f = 0; f < 256; ++f)
    acc += b2f(xs[ii][f]) * Wo[f * 16 + c];
  int i = i0 + ii;
  h2T[(size_t)c * N + i] = f2b(acc);
  float u1 = acc * ao[c];
  float u2 = acc * ao[16 + c];
  #pragma unroll
  for (int off = 8; off; off >>= 1){
    u1 += __shfl_down(u1, off, 16);
    u2 += __shfl_down(u2, off, 16);
  }
  if (c == 0){ f1o[i] = u1; f2o[i] = u2; }
  if (t < 16) h2T[(size_t)16 * N + i0 + t] = 0x3F80;      // ones row
  if (t < 240){                                            // zero rows 17..31
    int p = 17 + t / 16, io = t % 16;
    h2T[(size_t)p * N + i0 + io] = 0;
  }
}

// ---------------------------------------------------------------- k6: phase-B masked-softmax GEMM
__global__ __launch_bounds__(256) void k6_attB(const int* __restrict__ adj,
    const uint16_t* __restrict__ h2T, const float* __restrict__ f1o,
    const float* __restrict__ f2o, float* __restrict__ accB)
{
  __shared__ uint16_t Pl[64][48];
  __shared__ uint16_t Hl[32][48];
  __shared__ float f1s[64];

  const int t = threadIdx.x;
  const int ibl = blockIdx.x >> 3;
  const int js = blockIdx.x & 7;
  const int gi0 = ibl * 64;
  if (t < 64) f1s[t] = f1o[gi0 + t];

  const int tj = t & 31;
  const int half = t >> 5;
  const int lane = t & 63;
  const int wid = t >> 6;
  const int m = lane & 15;
  const int q = lane >> 4;

  f32x4 acc0 = {0.f, 0.f, 0.f, 0.f}, acc1 = {0.f, 0.f, 0.f, 0.f};
  const int* arow0 = adj + (size_t)(gi0 + half) * N + tj;

  for (int jc = 0; jc < 32; ++jc){
    const int gj = js * 1024 + jc * 32;
    float f2v = f2o[gj + tj];
    int av[8];
    #pragma unroll
    for (int r = 0; r < 8; ++r) av[r] = arow0[(size_t)(8 * r) * N + gj];

    __syncthreads();
    if (t < 128){
      int p = t >> 2, o4 = t & 3;
      *(uint4*)&Hl[p][o4 * 8] = *(const uint4*)(h2T + (size_t)p * N + gj + o4 * 8);
    }
    #pragma unroll
    for (int r = 0; r < 8; ++r){
      int i = half + 8 * r;
      float s = f1s[i] + f2v;
      float w = (av[r] > 0) ? __expf(lrelu(s, 0.2f)) : 0.f;
      Pl[i][tj] = f2b(w);
    }
    __syncthreads();

    bf16x8 af = *(const bf16x8*)&Pl[wid * 16 + m][q * 8];
    bf16x8 b0 = *(const bf16x8*)&Hl[m][q * 8];
    bf16x8 b1 = *(const bf16x8*)&Hl[16 + m][q * 8];
    acc0 = __builtin_amdgcn_mfma_f32_16x16x32_bf16(af, b0, acc0, 0, 0, 0);
    acc1 = __builtin_amdgcn_mfma_f32_16x16x32_bf16(af, b1, acc1, 0, 0, 0);
  }

  #pragma unroll
  for (int reg = 0; reg < 4; ++reg){
    int gi = gi0 + wid * 16 + q * 4 + reg;
    accB[((size_t)js * N + gi) * C2 + m] = acc0[reg];
    accB[((size_t)js * N + gi) * C2 + 16 + m] = acc1[reg];
  }
}

// ---------------------------------------------------------------- k7: reduce -> out (fp32)
__global__ void k7_redB(const float* __restrict__ accB, float* __restrict__ out){
  int idx = blockIdx.x * 256 + threadIdx.x;   // 131072
  int i = idx >> 4, c = idx & 15;
  float v = 0.f, Z = 0.f;
  #pragma unroll
  for (int js = 0; js < 8; ++js){
    const float* p = accB + ((size_t)js * N + i) * C2;
    v += p[c];
    Z += p[16];
  }
  out[idx] = v / Z;
}

// ================================================================ launch
extern "C" void kernel_launch(void* const* d_in, const int* in_sizes, int n_in,
                              void* d_out, int out_size, void* d_ws, size_t ws_size,
                              hipStream_t stream)
{
  const float* x   = (const float*)d_in[0];
  const int*   adj = (const int*)d_in[1];
  const float* Wh  = (const float*)d_in[2];
  const float* ah  = (const float*)d_in[3];
  const float* Wo  = (const float*)d_in[4];
  const float* ao  = (const float*)d_in[5];
  float* out = (float*)d_out;

  char* ws = (char*)d_ws;
  float*    WhT  = (float*)   (ws);                 // 512 KB  [4][64][512] fp32
  uint16_t* H    = (uint16_t*)(ws + 524288);        // 4 MB    [8192][256] bf16
  uint16_t* HT   = (uint16_t*)(ws + 4718592);       // 5 MB    [4][80][8192] bf16
  float*    f1   = (float*)   (ws + 9961472);       // 128 KB
  float*    f2   = (float*)   (ws + 10092544);      // 128 KB
  float*    accA = (float*)   (ws + 10223616);      // 40 MB   [4][8192][320]
  uint16_t* xcat = (uint16_t*)(ws + 52166656);      // 4 MB    [8192][256] bf16
  uint16_t* h2T  = (uint16_t*)(ws + 56360960);      // 512 KB  [32][8192] bf16
  float*    f1o  = (float*)   (ws + 56885248);      // 32 KB
  float*    f2o  = (float*)   (ws + 56918016);      // 32 KB
  float*    accB = (float*)   (ws + 56950784);      // 8 MB    [8][8192][32]  (end 65339392)

  hipLaunchKernelGGL(k0_wht,   dim3(512),  dim3(256), 0, stream, Wh, WhT);
  hipLaunchKernelGGL(k1_h,     dim3(1024), dim3(256), 0, stream, x, WhT, ah, H, f1, f2);
  hipLaunchKernelGGL(k2a_htT,  dim3(512),  dim3(256), 0, stream, H, HT);
  hipLaunchKernelGGL(k2b_fill, dim3(256),  dim3(256), 0, stream, HT);
  hipLaunchKernelGGL(k3_attA,  dim3(512),  dim3(256), 0, stream, adj, HT, f1, f2, accA);
  hipLaunchKernelGGL(k4_redA,  dim3(8192), dim3(256), 0, stream, accA, xcat);
  hipLaunchKernelGGL(k5_h2,    dim3(512),  dim3(256), 0, stream, xcat, Wo, ao, h2T, f1o, f2o);
  hipLaunchKernelGGL(k6_attB,  dim3(1024), dim3(256), 0, stream, adj, h2T, f1o, f2o, accB);
  hipLaunchKernelGGL(k7_redB,  dim3(512),  dim3(256), 0, stream, accB, out);
}